// Round 8
// baseline (303.372 us; speedup 1.0000x reference)
//
#include <hip/hip_runtime.h>

typedef __attribute__((ext_vector_type(8))) short bf16x8;
typedef __attribute__((ext_vector_type(4))) float f32x4;
typedef __attribute__((ext_vector_type(16))) float f32x16;

__device__ __forceinline__ unsigned short f2bf(float f) {
  union { float f; unsigned u; } a; a.f = f;
  unsigned u = a.u;
  u += 0x7fffu + ((u >> 16) & 1u);   // round-to-nearest-even
  return (unsigned short)(u >> 16);
}
__device__ __forceinline__ unsigned pk(float a, float b) {
  return (unsigned)f2bf(a) | ((unsigned)f2bf(b) << 16);
}

// ---------------------------------------------------------------------------
// Prep: build Bt[tap][n][k] bf16 in workspace.
//   n = opc*4 + q_out  (q minor -> acc regs = quaternion comps)
//   k = c*4   + q_in   (q minor -> one float4 pixel-channel = 8B of k)
// ---------------------------------------------------------------------------
__global__ void prep_bt(const float* __restrict__ wr, const float* __restrict__ wi,
                        const float* __restrict__ wj, const float* __restrict__ wk,
                        unsigned short* __restrict__ btg) {
  int idx = blockIdx.x * 256 + threadIdx.x;          // 9*256*256 = 589824
  if (idx >= 9 * 256 * 256) return;
  int tap = idx >> 16;
  int rem = idx & 65535;
  int n = rem >> 8, k = rem & 255;
  int opc = n >> 2, qo = n & 3, c = k >> 2, qi = k & 3;
  const int   comp[4][4] = {{0,1,2,3},{1,0,3,2},{2,3,0,1},{3,2,1,0}};
  const float sgn [4][4] = {{1.f,-1.f,-1.f,-1.f},{1.f,1.f,-1.f,1.f},
                            {1.f,1.f,1.f,-1.f},{1.f,-1.f,1.f,1.f}};
  int ci = comp[qo][qi];
  const float* wp = (ci == 0) ? wr : (ci == 1) ? wi : (ci == 2) ? wj : wk;
  float v = sgn[qo][qi] * wp[(opc * 64 + c) * 9 + tap];
  btg[idx] = f2bf(v);
}

// ---------------------------------------------------------------------------
// Main: implicit-GEMM quaternion conv, 32x32x16 MFMA, mega-chunk structure.
// Block: 512 threads = 8 waves; tile = 256 px (4 image rows) x 256 N.
// Wave (wm, wn): 128 px (2 image rows) x 64 N. acc[2][4] = 128 AGPR.
// Grid 256 = exactly 1 block/CU.
// K split into 2 MEGA chunks of 32 channels (k=128). Per mega: stage the full
// 6-row x 66-col x 32-ch window (99KB LDS) ONCE, then an UNINTERRUPTED
// 72-cluster (9 taps x 8 kst) MFMA stretch with zero barriers. 3 barriers
// per block total. pf/wf double-buffered cluster-to-cluster (static parity).
// LDS k-slot-major, conflict-free: xw[row 0..5][ks8 0..15][col 0..65] x 16B.
// Weights per-fragment from L2-resident btg (604MB total = 17.5us L2).
// ---------------------------------------------------------------------------
__launch_bounds__(512, 2)
__global__ void qconv_main(const float* __restrict__ x,
                           const unsigned short* __restrict__ btg,
                           const float* __restrict__ bias,
                           float* __restrict__ out) {
  __shared__ char xw[6 * 16 * 66 * 16];   // 101376 B

  const int tid = threadIdx.x;
  // XCD-aware swizzle: 256 blocks, 8 XCDs -> 32 consecutive per XCD
  const int nb  = (blockIdx.x & 7) * 32 + (blockIdx.x >> 3);
  const int b   = nb >> 4;              // image
  const int h0  = (nb & 15) * 4;        // first of 4 image rows

  const int lane = tid & 63;
  const int wid  = tid >> 6;            // 0..7
  const int wm   = wid & 1;             // pixel half (2 image rows)
  const int wn   = wid >> 1;            // 0..3: N quarter
  const int l31  = lane & 31;
  const int l32  = lane >> 5;

  const int w_   = tid & 63;            // staging column 0..63
  const int rgrp = tid >> 6;            // staging group 0..7

  // zero-fill padding cols 0 and 65: 6 rows x 16 ks8 x 2 sides = 192 cells
  if (tid < 192) {
    int row = tid >> 5, rem = tid & 31, ks8 = rem >> 1;
    int col = (rem & 1) ? 65 : 0;
    *reinterpret_cast<f32x4*>(xw + ((row * 16 + ks8) * 66 + col) * 16) =
        (f32x4){0.f, 0.f, 0.f, 0.f};
  }

  f32x16 acc[2][4];
#pragma unroll
  for (int i = 0; i < 2; ++i)
#pragma unroll
    for (int j = 0; j < 4; ++j)
      acc[i][j] = (f32x16)(0.f);

  // pf fragment: cluster (T,K), fm: row6 = 2wm + (fm>>1) + dh + 1
#define LOADPF(DST, T, K)                                                      \
  do {                                                                         \
    const int dh_ = (T) / 3 - 1, dw_ = (T) % 3 - 1;                            \
    _Pragma("unroll")                                                          \
    for (int fm = 0; fm < 4; ++fm) {                                           \
      int row6 = 2 * wm + (fm >> 1) + dh_ + 1;                                 \
      int col  = (fm & 1) * 32 + l31 + dw_ + 1;                                \
      DST[fm] = *reinterpret_cast<const bf16x8*>(                              \
          xw + ((row6 * 16 + (K)*2 + l32) * 66 + col) * 16);                   \
    }                                                                          \
  } while (0)

#define LOADWF(DST, T, K)                                                      \
  do {                                                                         \
    _Pragma("unroll")                                                          \
    for (int fn = 0; fn < 2; ++fn)                                             \
      DST[fn] = *reinterpret_cast<const bf16x8*>(                              \
          wb + (T)*65536 + fn * 8192 + (K)*16);                                \
  } while (0)

#define MFMAS(WF, PF)                                                          \
  do {                                                                         \
    _Pragma("unroll")                                                          \
    for (int fn = 0; fn < 2; ++fn)                                             \
      _Pragma("unroll")                                                        \
      for (int fm = 0; fm < 4; ++fm)                                           \
        acc[fn][fm] = __builtin_amdgcn_mfma_f32_32x32x16_bf16(                 \
            WF[fn], PF[fm], acc[fn][fm], 0, 0, 0);                             \
  } while (0)

  for (int mega = 0; mega < 2; ++mega) {
    __syncthreads();   // pad fill (mega 0) / all reads of prev mega done

    // ---- stage full window: 6 rows x 64 cols x 32 ch (pair per cell) ----
#pragma unroll
    for (int i = 0; i < 12; ++i) {
      int idx = rgrp * 12 + i;           // 0..95
      int row = idx >> 4, ks8 = idx & 15;
      int hp  = h0 + row - 1;
      int c   = mega * 32 + ks8 * 2;
      float4 v0 = make_float4(0.f, 0.f, 0.f, 0.f), v1 = v0;
      if (hp >= 0 && hp < 64) {
        const float* p =
            x + (size_t)((((b * 64 + c) * 64 + hp) * 64 + w_) * 4);
        v0 = *reinterpret_cast<const float4*>(p);
        v1 = *reinterpret_cast<const float4*>(p + 16384);  // next channel
      }
      uint4 u = make_uint4(pk(v0.x, v0.y), pk(v0.z, v0.w),
                           pk(v1.x, v1.y), pk(v1.z, v1.w));
      *reinterpret_cast<uint4*>(
          xw + ((row * 16 + ks8) * 66 + (w_ + 1)) * 16) = u;
    }
    __syncthreads();   // window ready

    // weight element base (u16): frag (T,K,fn) at wb + T*65536 + fn*8192 + K*16
    const unsigned short* wb =
        btg + (size_t)(wn * 64 + l31) * 256 + mega * 128 + l32 * 8;

    bf16x8 pfA[4], pfB[4], wfA[2], wfB[2];
    LOADPF(pfA, 0, 0);
    LOADWF(wfA, 0, 0);

    // ---- 72 clusters, zero barriers, cluster-ahead double buffering ----
#pragma unroll
    for (int t = 0; t < 9; ++t) {
#pragma unroll
      for (int k = 0; k < 8; ++k) {
        const int ci  = t * 8 + k;           // 0..71, compile-time
        const int nt2 = (k == 7) ? t + 1 : t;
        const int nk  = (k == 7) ? 0 : k + 1;
        if (ci & 1) {
          if (ci != 71) { LOADPF(pfA, nt2, nk); LOADWF(wfA, nt2, nk); }
          MFMAS(wfB, pfB);
        } else {
          if (ci != 71) { LOADPF(pfB, nt2, nk); LOADWF(wfB, nt2, nk); }
          MFMAS(wfA, pfA);
        }
      }
    }
  }

  // ---- epilogue: D row=(reg&3)+8*(reg>>2)+4*l32 -> reg&3 == q component ----
#pragma unroll
  for (int fn = 0; fn < 2; ++fn) {
#pragma unroll
    for (int fm = 0; fm < 4; ++fm) {
      int w = (fm & 1) * 32 + l31;
      int h = h0 + 2 * wm + (fm >> 1);
#pragma unroll
      for (int g = 0; g < 4; ++g) {
        int opc = wn * 16 + fn * 8 + g * 2 + l32;
        f32x4 v = {acc[fn][fm][4 * g + 0], acc[fn][fm][4 * g + 1],
                   acc[fn][fm][4 * g + 2], acc[fn][fm][4 * g + 3]};
        v.x += bias[opc];   // bias only on real component
        *reinterpret_cast<f32x4*>(
            out + (size_t)((((b * 64 + opc) * 64 + h) * 64 + w) * 4)) = v;
      }
    }
  }
#undef LOADPF
#undef LOADWF
#undef MFMAS
}

extern "C" void kernel_launch(void* const* d_in, const int* in_sizes, int n_in,
                              void* d_out, int out_size, void* d_ws, size_t ws_size,
                              hipStream_t stream) {
  const float* x    = (const float*)d_in[0];
  const float* wr   = (const float*)d_in[1];
  const float* wi   = (const float*)d_in[2];
  const float* wj   = (const float*)d_in[3];
  const float* wk   = (const float*)d_in[4];
  const float* bias = (const float*)d_in[5];
  unsigned short* btg = (unsigned short*)d_ws;   // 9*256*256*2 = 1.18 MB

  prep_bt<<<2304, 256, 0, stream>>>(wr, wi, wj, wk, btg);
  qconv_main<<<256, 512, 0, stream>>>(x, btg, bias, (float*)d_out);
}

// Round 9
// 123.559 us; speedup vs baseline: 2.4553x; 2.4553x over previous
//
#include <hip/hip_runtime.h>

typedef __attribute__((ext_vector_type(8))) short bf16x8;
typedef __attribute__((ext_vector_type(4))) float f32x4;
typedef __attribute__((ext_vector_type(16))) float f32x16;

__device__ __forceinline__ unsigned short f2bf(float f) {
  union { float f; unsigned u; } a; a.f = f;
  unsigned u = a.u;
  u += 0x7fffu + ((u >> 16) & 1u);
  return (unsigned short)(u >> 16);
}
__device__ __forceinline__ unsigned pk(float a, float b) {
  return (unsigned)f2bf(a) | ((unsigned)f2bf(b) << 16);
}
__device__ __forceinline__ void gload_lds16(const void* g, void* l) {
  __builtin_amdgcn_global_load_lds(
      (const __attribute__((address_space(1))) void*)g,
      (__attribute__((address_space(3))) void*)l, 16, 0, 0);
}

__global__ void prep_bt(const float* __restrict__ wr, const float* __restrict__ wi,
                        const float* __restrict__ wj, const float* __restrict__ wk,
                        unsigned short* __restrict__ btg) {
  int idx = blockIdx.x * 256 + threadIdx.x;
  if (idx >= 9 * 256 * 256) return;
  int tap = idx >> 16;
  int rem = idx & 65535;
  int n = rem >> 8, k = rem & 255;
  int opc = n >> 2, qo = n & 3, c = k >> 2, qi = k & 3;
  const int   comp[4][4] = {{0,1,2,3},{1,0,3,2},{2,3,0,1},{3,2,1,0}};
  const float sgn [4][4] = {{1.f,-1.f,-1.f,-1.f},{1.f,1.f,-1.f,1.f},
                            {1.f,1.f,1.f,-1.f},{1.f,-1.f,1.f,1.f}};
  int ci = comp[qo][qi];
  const float* wp = (ci == 0) ? wr : (ci == 1) ? wi : (ci == 2) ? wj : wk;
  float v = sgn[qo][qi] * wp[(opc * 64 + c) * 9 + tap];
  btg[idx] = f2bf(v);
}

__launch_bounds__(512, 2)
__global__ void qconv_main(const float* __restrict__ x,
                           const unsigned short* __restrict__ btg,
                           const float* __restrict__ bias,
                           float* __restrict__ out) {
#define XBUF_SZ 25344
#define WBUF_SZ 16384
  __shared__ char lds[2 * XBUF_SZ + 3 * WBUF_SZ];   // 99840 B
  char* wring = lds + 2 * XBUF_SZ;

  const int tid = threadIdx.x;
  const int nb  = (blockIdx.x & 7) * 32 + (blockIdx.x >> 3);
  const int b   = nb >> 4;
  const int h0  = (nb & 15) * 4;

  const int lane = tid & 63;
  const int wid  = tid >> 6;
  const int wm   = wid & 1;
  const int wn   = wid >> 1;
  const int l31  = lane & 31;
  const int l32  = lane >> 5;

  if (tid < 96) {
    int par = tid / 48, r = tid % 48;
    int row = r >> 3, ks = (r >> 1) & 3, side = r & 1;
    *reinterpret_cast<f32x4*>(
        lds + par * XBUF_SZ + ((row * 4 + ks) * 66 + (side ? 65 : 0)) * 16) =
        (f32x4){0.f, 0.f, 0.f, 0.f};
  }

  f32x16 acc[2][4];
#pragma unroll
  for (int i = 0; i < 2; ++i)
#pragma unroll
    for (int j = 0; j < 4; ++j)
      acc[i][j] = (f32x16)(0.f);

  float4 xr[6];

#define XISSUE(CH)                                                             \
  do {                                                                         \
    _Pragma("unroll") for (int j = 0; j < 3; ++j) {                            \
      int ci_ = j * 512 + tid;                                                 \
      int row_ = ci_ >> 8, ks_ = (ci_ >> 6) & 3, c64_ = ci_ & 63;              \
      int hp_ = h0 + row_ - 1;                                                 \
      int c_  = (CH) * 8 + ks_ * 2;                                            \
      float4 a_ = make_float4(0.f, 0.f, 0.f, 0.f), b_ = a_;                    \
      if (hp_ >= 0 && hp_ < 64) {                                              \
        const float* p_ =                                                      \
            x + (size_t)((((b * 64 + c_) * 64 + hp_) * 64 + c64_) * 4);        \
        a_ = *reinterpret_cast<const float4*>(p_);                             \
        b_ = *reinterpret_cast<const float4*>(p_ + 16384);                     \
      }                                                                        \
      xr[2 * j] = a_; xr[2 * j + 1] = b_;                                      \
    }                                                                          \
    __builtin_amdgcn_sched_barrier(0);                                         \
  } while (0)

#define XWRITE(PAR)                                                            \
  do {                                                                         \
    char* xd_ = lds + (PAR) * XBUF_SZ;                                         \
    _Pragma("unroll") for (int j = 0; j < 3; ++j) {                            \
      int ci_ = j * 512 + tid;                                                 \
      int row_ = ci_ >> 8, ks_ = (ci_ >> 6) & 3, c64_ = ci_ & 63;              \
      uint4 u_ = make_uint4(pk(xr[2 * j].x, xr[2 * j].y),                      \
                            pk(xr[2 * j].z, xr[2 * j].w),                      \
                            pk(xr[2 * j + 1].x, xr[2 * j + 1].y),              \
                            pk(xr[2 * j + 1].z, xr[2 * j + 1].w));             \
      *reinterpret_cast<uint4*>(                                               \
          xd_ + ((row_ * 4 + ks_) * 66 + c64_ + 1) * 16) = u_;                 \
    }                                                                          \
  } while (0)

#define WISSUE(TAP, CH, RING)                                                  \
  do {                                                                         \
    _Pragma("unroll") for (int j = 0; j < 2; ++j) {                            \
      int p_ = j * 512 + wid * 64 + lane;                                      \
      int n_ = p_ & 255, ks_ = p_ >> 8;                                        \
      const unsigned short* g_ =                                               \
          btg + ((size_t)(TAP) * 256 + n_) * 256 + (CH) * 32 + ks_ * 8;        \
      char* l_ = wring + (RING) * WBUF_SZ + (j * 512 + wid * 64) * 16;         \
      gload_lds16(g_, l_);                                                     \
    }                                                                          \
    __builtin_amdgcn_sched_barrier(0);                                         \
  } while (0)

#define PHASE(T, VMSTR, DO_W, WTAP, WCH, DO_X, DO_CVT)                         \
  {                                                                            \
    const int dh_ = (T) / 3 - 1, dw_ = (T) % 3 - 1;                            \
    bf16x8 pf[2][4], wf[2][2];                                                 \
    const char* wr_ = wring + ((T) % 3) * WBUF_SZ;                             \
    _Pragma("unroll") for (int kst = 0; kst < 2; ++kst) {                      \
      _Pragma("unroll") for (int fm = 0; fm < 4; ++fm) {                       \
        int row6 = 2 * wm + (fm >> 1) + dh_ + 1;                               \
        int col  = (fm & 1) * 32 + l31 + dw_ + 1;                              \
        pf[kst][fm] = *reinterpret_cast<const bf16x8*>(                        \
            xc + ((row6 * 4 + kst * 2 + l32) * 66 + col) * 16);                \
      }                                                                        \
      _Pragma("unroll") for (int fn = 0; fn < 2; ++fn)                         \
        wf[kst][fn] = *reinterpret_cast<const bf16x8*>(                        \
            wr_ + ((kst * 2 + l32) * 256 + wn * 64 + fn * 32 + l31) * 16);     \
    }                                                                          \
    if (DO_W) WISSUE(WTAP, WCH, ((T) + 2) % 3);                                \
    if (DO_X) XISSUE(h + 1);                                                   \
    if (DO_CVT) XWRITE((h + 1) & 1);                                           \
    asm volatile("s_waitcnt lgkmcnt(0)" ::: "memory");                         \
    asm volatile("s_waitcnt " VMSTR ::: "memory");                             \
    __builtin_amdgcn_s_barrier();                                              \
    __builtin_amdgcn_sched_barrier(0);                                         \
    __builtin_amdgcn_s_setprio(1);                                             \
    _Pragma("unroll") for (int kst = 0; kst < 2; ++kst)                        \
      _Pragma("unroll") for (int fn = 0; fn < 2; ++fn)                         \
        _Pragma("unroll") for (int fm = 0; fm < 4; ++fm)                       \
          acc[fn][fm] = __builtin_amdgcn_mfma_f32_32x32x16_bf16(               \
              wf[kst][fn], pf[kst][fm], acc[fn][fm], 0, 0, 0);                 \
    __builtin_amdgcn_s_setprio(0);                                             \
  }

  // ---- prologue: X chunk 0 -> xbuf0; W taps 0,1 -> rings 0,1 ----
  XISSUE(0);
  WISSUE(0, 0, 0);
  WISSUE(1, 0, 1);
  XWRITE(0);
  asm volatile("s_waitcnt lgkmcnt(0)" ::: "memory");
  asm volatile("s_waitcnt vmcnt(2)" ::: "memory");
  __builtin_amdgcn_s_barrier();
  __builtin_amdgcn_sched_barrier(0);

#pragma unroll 1
  for (int h = 0; h < 7; ++h) {
    const char* xc = lds + (h & 1) * XBUF_SZ;
    PHASE(0, "vmcnt(2)", 1, 2, h, 0, 0)
    PHASE(1, "vmcnt(2)", 1, 3, h, 0, 0)
    PHASE(2, "vmcnt(2)", 1, 4, h, 0, 0)
    PHASE(3, "vmcnt(2)", 1, 5, h, 0, 0)
    PHASE(4, "vmcnt(2)", 1, 6, h, 0, 0)
    PHASE(5, "vmcnt(8)", 1, 7, h, 1, 0)
    PHASE(6, "vmcnt(8)", 1, 8, h, 0, 0)
    PHASE(7, "vmcnt(2)", 1, 0, h + 1, 0, 0)
    PHASE(8, "vmcnt(2)", 1, 1, h + 1, 0, 1)
  }
  {
    const int h = 7;
    const char* xc = lds + (h & 1) * XBUF_SZ;
    PHASE(0, "vmcnt(2)", 1, 2, h, 0, 0)
    PHASE(1, "vmcnt(2)", 1, 3, h, 0, 0)
    PHASE(2, "vmcnt(2)", 1, 4, h, 0, 0)
    PHASE(3, "vmcnt(2)", 1, 5, h, 0, 0)
    PHASE(4, "vmcnt(2)", 1, 6, h, 0, 0)
    PHASE(5, "vmcnt(2)", 1, 7, h, 0, 0)
    PHASE(6, "vmcnt(2)", 1, 8, h, 0, 0)
    PHASE(7, "vmcnt(0)", 0, 0, 0, 0, 0)
    PHASE(8, "vmcnt(0)", 0, 0, 0, 0, 0)
  }

#pragma unroll
  for (int fn = 0; fn < 2; ++fn) {
#pragma unroll
    for (int fm = 0; fm < 4; ++fm) {
      int w  = (fm & 1) * 32 + l31;
      int hh = h0 + 2 * wm + (fm >> 1);
#pragma unroll
      for (int g = 0; g < 4; ++g) {
        int opc = wn * 16 + fn * 8 + g * 2 + l32;
        f32x4 v = {acc[fn][fm][4 * g + 0], acc[fn][fm][4 * g + 1],
                   acc[fn][fm][4 * g + 2], acc[fn][fm][4 * g + 3]};
        v.x += bias[opc];
        *reinterpret_cast<f32x4*>(
            out + (size_t)((((b * 64 + opc) * 64 + hh) * 64 + w) * 4)) = v;
      }
    }
  }
#undef PHASE
#undef WISSUE
#undef XWRITE
#undef XISSUE
#undef XBUF_SZ
#undef WBUF_SZ
}

extern "C" void kernel_launch(void* const* d_in, const int* in_sizes, int n_in,
                              void* d_out, int out_size, void* d_ws, size_t ws_size,
                              hipStream_t stream) {
  const float* x    = (const float*)d_in[0];
  const float* wr   = (const float*)d_in[1];
  const float* wi   = (const float*)d_in[2];
  const float* wj   = (const float*)d_in[3];
  const float* wk   = (const float*)d_in[4];
  const float* bias = (const float*)d_in[5];
  unsigned short* btg = (unsigned short*)d_ws;

  prep_bt<<<2304, 256, 0, stream>>>(wr, wi, wj, wk, btg);
  qconv_main<<<256, 512, 0, stream>>>(x, btg, bias, (float*)d_out);
}